// Round 2
// baseline (1334.525 us; speedup 1.0000x reference)
//
#include <hip/hip_runtime.h>
#include <math.h>

#define T_STEPS 12
#define HID 64
#define NODES 16   // nodes per wave in gru_all

__device__ __forceinline__ float sigmoidf_(float x){ return 1.0f/(1.0f + __expf(-x)); }
__device__ __forceinline__ float tanhf_(float x){
  float e = __expf(-2.0f * fabsf(x));
  float t = (1.0f - e) / (1.0f + e);
  return copysignf(t, x);
}

// --- CSR build ---------------------------------------------------------
__global__ void count_kernel(const int* __restrict__ ei, int E, int* __restrict__ cnt){
  int e = blockIdx.x*blockDim.x + threadIdx.x;
  if (e < E) atomicAdd(&cnt[ei[E + e]], 1);
}

__global__ void dinv_kernel(const int* __restrict__ cnt, float* __restrict__ dinv, int N){
  int i = blockIdx.x*blockDim.x + threadIdx.x;
  if (i < N) dinv[i] = 1.0f / sqrtf((float)cnt[i] + 1.0f);
}

// hierarchical scan: per-1024-block inclusive scan + block sums
__global__ void scan1_kernel(const int* __restrict__ cnt, int* __restrict__ part,
                             int* __restrict__ bsum, int N){
  __shared__ int sm[1024];
  int tid = threadIdx.x;
  int g = blockIdx.x*1024 + tid;
  int v = (g < N) ? cnt[g] : 0;
  sm[tid] = v; __syncthreads();
  for (int off = 1; off < 1024; off <<= 1){
    int t = (tid >= off) ? sm[tid-off] : 0;
    __syncthreads();
    sm[tid] += t;
    __syncthreads();
  }
  if (g < N) part[g] = sm[tid];
  if (tid == 1023) bsum[blockIdx.x] = sm[1023];
}

// scan block sums (nb <= 64), single wave, inclusive
__global__ void scan2_kernel(const int* __restrict__ bsum, int* __restrict__ bincl, int nb){
  int lane = threadIdx.x;
  int v = (lane < nb) ? bsum[lane] : 0;
  #pragma unroll
  for (int off = 1; off < 64; off <<= 1){
    int u = __shfl_up(v, off, 64);
    if (lane >= off) v += u;
  }
  if (lane < nb) bincl[lane] = v;
}

__global__ void scan3_kernel(const int* __restrict__ part, const int* __restrict__ bincl,
                             const int* __restrict__ cnt, int* __restrict__ row_start,
                             int* __restrict__ cursor, int N){
  int g = blockIdx.x*blockDim.x + threadIdx.x;
  if (g < N){
    int b = g >> 10;
    int incl = part[g] + (b ? bincl[b-1] : 0);
    int excl = incl - cnt[g];
    row_start[g] = excl;
    cursor[g]    = excl;
    if (g == N-1) row_start[N] = incl;
  }
}

__global__ void fill_kernel(const int* __restrict__ ei, int E,
                            int* __restrict__ cursor, int* __restrict__ csr){
  int e = blockIdx.x*blockDim.x + threadIdx.x;
  if (e < E){
    int dst = ei[E + e];
    int pos = atomicAdd(&cursor[dst], 1);
    csr[pos] = ei[e];  // src
  }
}

// Pack W_ih/W_hh (each 192x64 row-major) into fully-dense k-pair layout:
// for pair p (k0=2p, k1=2p+1), three float4 "planes", each plane coalesced over j:
//   plane0[j] = {ir(k0), iz(k0), in(k0), hr(k0)}
//   plane1[j] = {hz(k0), hn(k0), ir(k1), iz(k1)}
//   plane2[j] = {in(k1), hr(k1), hz(k1), hn(k1)}
// flat float index: ((p*3 + w)*64 + j)*4 + f, with c = w*4+f in [0,12)
__global__ void pack_kernel(const float* __restrict__ W_ih, const float* __restrict__ W_hh,
                            float* __restrict__ Wp){
  int idx = blockIdx.x*blockDim.x + threadIdx.x; // 0..24575
  if (idx >= 32*64*12) return;
  int f = idx & 3;
  int j = (idx >> 2) & 63;
  int q = idx >> 8;          // p*3 + w
  int w = q % 3;
  int p = q / 3;
  int c = w*4 + f;
  int k = 2*p + (c >= 6 ? 1 : 0);
  int cc = c % 6;
  float val;
  if (cc < 3) val = W_ih[(cc*HID + j)*HID + k];
  else        val = W_hh[((cc-3)*HID + j)*HID + k];
  Wp[idx] = val;
}

// GCN aggregation in INPUT space, all 12 timesteps at once.
__global__ void gather_kernel(const float* __restrict__ x, const int* __restrict__ row_start,
                              const int* __restrict__ csr, const float* __restrict__ dinv,
                              float* __restrict__ rin, int N){
  int lane = threadIdx.x & 63;
  int n = blockIdx.x*4 + (threadIdx.x >> 6);
  if (n >= N) return;
  int s0 = row_start[n], s1 = row_start[n+1];
  float acc = 0.f;
  for (int e = s0; e < s1; ++e){
    int s = csr[e];
    float dv = dinv[s];
    if (lane < 24) acc += dv * x[s*24 + lane];
  }
  if (lane < 24){
    float dn = dinv[n];
    float self = x[n*24 + lane];
    rin[n*24 + lane] = dn*acc + dn*dn*self;
  }
}

// All 12 GRU steps + final FC, fused. Wave = NODES(16) nodes; lane j = channel j.
// h never leaves registers. Shared r/z accumulators (ih+hh summed in-place).
__global__ __launch_bounds__(256, 3) void gru_all_kernel(
    const float* __restrict__ rin,
    const float* __restrict__ W_gcn, const float* __restrict__ b_gcn,
    const float* __restrict__ Wp,
    const float* __restrict__ b_ih, const float* __restrict__ b_hh,
    const float* __restrict__ W_fc, const float* __restrict__ b_fc,
    float* __restrict__ out, int N){
  int lane = threadIdx.x & 63;
  int wid  = threadIdx.x >> 6;
  int n0 = (blockIdx.x*4 + wid)*NODES;
  if (n0 >= N) return;

  float wg0 = W_gcn[lane], wg1 = W_gcn[HID+lane], bg = b_gcn[lane];
  float bir = b_ih[lane], biz = b_ih[HID+lane], bin = b_ih[2*HID+lane];
  float bhr = b_hh[lane], bhz = b_hh[HID+lane], bhn = b_hh[2*HID+lane];
  float brz_r = bir + bhr, brz_z = biz + bhz;

  float h[NODES];
  #pragma unroll
  for (int i = 0; i < NODES; ++i) h[i] = 0.f;

  const float4* Wp4 = (const float4*)Wp;

  #pragma unroll 1
  for (int t = 0; t < T_STEPS; ++t){
    // spatial rep for this step: s = relu(rin @ W_gcn + b_gcn), per node scalar pair
    float s[NODES];
    #pragma unroll
    for (int i = 0; i < NODES; ++i){
      int n = n0 + i;
      float r0 = (n < N) ? rin[n*24 + 2*t]     : 0.f;
      float r1 = (n < N) ? rin[n*24 + 2*t + 1] : 0.f;
      s[i] = fmaxf(fmaf(r0, wg0, fmaf(r1, wg1, bg)), 0.f);
    }

    float ar[NODES], az[NODES], ani[NODES], anh[NODES];
    #pragma unroll
    for (int i = 0; i < NODES; ++i){ ar[i]=0.f; az[i]=0.f; ani[i]=0.f; anh[i]=0.f; }

    #pragma unroll 2
    for (int p = 0; p < 32; ++p){
      float4 w0 = Wp4[(p*3 + 0)*64 + lane];
      float4 w1 = Wp4[(p*3 + 1)*64 + lane];
      float4 w2 = Wp4[(p*3 + 2)*64 + lane];
      int k0 = 2*p, k1 = 2*p + 1;
      #pragma unroll
      for (int i = 0; i < NODES; ++i){
        float sk0 = __shfl(s[i], k0, 64);
        float hk0 = __shfl(h[i], k0, 64);
        ar[i]  = fmaf(w0.x, sk0, ar[i]);
        az[i]  = fmaf(w0.y, sk0, az[i]);
        ani[i] = fmaf(w0.z, sk0, ani[i]);
        ar[i]  = fmaf(w0.w, hk0, ar[i]);
        az[i]  = fmaf(w1.x, hk0, az[i]);
        anh[i] = fmaf(w1.y, hk0, anh[i]);
        float sk1 = __shfl(s[i], k1, 64);
        float hk1 = __shfl(h[i], k1, 64);
        ar[i]  = fmaf(w1.z, sk1, ar[i]);
        az[i]  = fmaf(w1.w, sk1, az[i]);
        ani[i] = fmaf(w2.x, sk1, ani[i]);
        ar[i]  = fmaf(w2.y, hk1, ar[i]);
        az[i]  = fmaf(w2.z, hk1, az[i]);
        anh[i] = fmaf(w2.w, hk1, anh[i]);
      }
    }

    #pragma unroll
    for (int i = 0; i < NODES; ++i){
      float r  = sigmoidf_(ar[i] + brz_r);
      float z  = sigmoidf_(az[i] + brz_z);
      float nn = tanhf_(ani[i] + bin + r*(anh[i] + bhn));
      h[i] = (1.0f - z)*nn + z*h[i];
    }
  }

  // fused FC: out[n] = dot(h[n], W_fc) + b_fc
  float wfc = W_fc[lane];
  float bfc = b_fc[0];
  #pragma unroll
  for (int i = 0; i < NODES; ++i){
    float v = h[i] * wfc;
    #pragma unroll
    for (int m = 32; m >= 1; m >>= 1) v += __shfl_xor(v, m, 64);
    int n = n0 + i;
    if (lane == 0 && n < N) out[n] = v + bfc;
  }
}

extern "C" void kernel_launch(void* const* d_in, const int* in_sizes, int n_in,
                              void* d_out, int out_size, void* d_ws, size_t ws_size,
                              hipStream_t stream){
  const float* x     = (const float*)d_in[0];
  const int*   ei    = (const int*)d_in[1];
  const float* W_gcn = (const float*)d_in[2];
  const float* b_gcn = (const float*)d_in[3];
  const float* W_ih  = (const float*)d_in[4];
  const float* W_hh  = (const float*)d_in[5];
  const float* b_ih  = (const float*)d_in[6];
  const float* b_hh  = (const float*)d_in[7];
  const float* W_fc  = (const float*)d_in[8];
  const float* b_fc  = (const float*)d_in[9];
  float* out = (float*)d_out;
  const int N = in_sizes[0] / (T_STEPS*2);
  const int E = in_sizes[1] / 2;
  const int NB1024 = (N + 1023) / 1024;

  char* p = (char*)d_ws;
  auto alloc = [&](size_t bytes)->char*{
    char* r = p; p += (bytes + 255) & ~(size_t)255; return r;
  };
  int*   cnt       = (int*)  alloc((size_t)N*4);
  int*   row_start = (int*)  alloc((size_t)(N+1)*4);
  int*   cursor    = (int*)  alloc((size_t)N*4);
  int*   csr       = (int*)  alloc((size_t)E*4);
  float* dinv      = (float*)alloc((size_t)N*4);
  int*   part      = (int*)  alloc((size_t)N*4);
  int*   bsum      = (int*)  alloc((size_t)NB1024*4);
  int*   bincl     = (int*)  alloc((size_t)NB1024*4);
  float* Wp        = (float*)alloc((size_t)32*64*12*4);
  float* rin       = (float*)alloc((size_t)N*24*4);

  hipMemsetAsync(cnt, 0, (size_t)N*4, stream);
  count_kernel<<<(E+255)/256, 256, 0, stream>>>(ei, E, cnt);
  dinv_kernel<<<(N+255)/256, 256, 0, stream>>>(cnt, dinv, N);
  scan1_kernel<<<NB1024, 1024, 0, stream>>>(cnt, part, bsum, N);
  scan2_kernel<<<1, 64, 0, stream>>>(bsum, bincl, NB1024);
  scan3_kernel<<<(N+255)/256, 256, 0, stream>>>(part, bincl, cnt, row_start, cursor, N);
  fill_kernel<<<(E+255)/256, 256, 0, stream>>>(ei, E, cursor, csr);
  pack_kernel<<<(32*64*12+255)/256, 256, 0, stream>>>(W_ih, W_hh, Wp);
  gather_kernel<<<(N+3)/4, 256, 0, stream>>>(x, row_start, csr, dinv, rin, N);

  int waves = (N + NODES - 1) / NODES;
  int blocks = (waves + 3) / 4;
  gru_all_kernel<<<blocks, 256, 0, stream>>>(rin, W_gcn, b_gcn, Wp, b_ih, b_hh,
                                             W_fc, b_fc, out, N);
}

// Round 3
// 1129.224 us; speedup vs baseline: 1.1818x; 1.1818x over previous
//
#include <hip/hip_runtime.h>
#include <math.h>

#define T_STEPS 12
#define HID 64
#define NODES 12          // nodes per wave in gru_all
#define WPB 8             // waves per block
#define BLOCK (WPB*64)    // 512 threads
#define NPB (WPB*NODES)   // 96 nodes per block

__device__ __forceinline__ float sigmoidf_(float x){ return 1.0f/(1.0f + __expf(-x)); }
__device__ __forceinline__ float tanhf_(float x){
  float e = __expf(-2.0f * fabsf(x));
  float t = (1.0f - e) / (1.0f + e);
  return copysignf(t, x);
}
// broadcast lane l of v to all lanes via v_readlane (uniform l, no LDS pipe)
__device__ __forceinline__ float rlane(float v, int l){
  return __int_as_float(__builtin_amdgcn_readlane(__float_as_int(v), l));
}

// --- CSR build ---------------------------------------------------------
__global__ void count_kernel(const int* __restrict__ ei, int E, int* __restrict__ cnt){
  int e = blockIdx.x*blockDim.x + threadIdx.x;
  if (e < E) atomicAdd(&cnt[ei[E + e]], 1);
}

__global__ void dinv_kernel(const int* __restrict__ cnt, float* __restrict__ dinv, int N){
  int i = blockIdx.x*blockDim.x + threadIdx.x;
  if (i < N) dinv[i] = 1.0f / sqrtf((float)cnt[i] + 1.0f);
}

__global__ void scan1_kernel(const int* __restrict__ cnt, int* __restrict__ part,
                             int* __restrict__ bsum, int N){
  __shared__ int sm[1024];
  int tid = threadIdx.x;
  int g = blockIdx.x*1024 + tid;
  int v = (g < N) ? cnt[g] : 0;
  sm[tid] = v; __syncthreads();
  for (int off = 1; off < 1024; off <<= 1){
    int t = (tid >= off) ? sm[tid-off] : 0;
    __syncthreads();
    sm[tid] += t;
    __syncthreads();
  }
  if (g < N) part[g] = sm[tid];
  if (tid == 1023) bsum[blockIdx.x] = sm[1023];
}

__global__ void scan2_kernel(const int* __restrict__ bsum, int* __restrict__ bincl, int nb){
  int lane = threadIdx.x;
  int v = (lane < nb) ? bsum[lane] : 0;
  #pragma unroll
  for (int off = 1; off < 64; off <<= 1){
    int u = __shfl_up(v, off, 64);
    if (lane >= off) v += u;
  }
  if (lane < nb) bincl[lane] = v;
}

__global__ void scan3_kernel(const int* __restrict__ part, const int* __restrict__ bincl,
                             const int* __restrict__ cnt, int* __restrict__ row_start,
                             int* __restrict__ cursor, int N){
  int g = blockIdx.x*blockDim.x + threadIdx.x;
  if (g < N){
    int b = g >> 10;
    int incl = part[g] + (b ? bincl[b-1] : 0);
    int excl = incl - cnt[g];
    row_start[g] = excl;
    cursor[g]    = excl;
    if (g == N-1) row_start[N] = incl;
  }
}

__global__ void fill_kernel(const int* __restrict__ ei, int E,
                            int* __restrict__ cursor, int* __restrict__ csr){
  int e = blockIdx.x*blockDim.x + threadIdx.x;
  if (e < E){
    int dst = ei[E + e];
    int pos = atomicAdd(&cursor[dst], 1);
    csr[pos] = ei[e];  // src
  }
}

// Pack W_ih/W_hh (each 192x64 row-major) into:
//   region A (first 4096 float4 = 64 KB, goes to LDS): for each pair p, two planes
//     q=2p:   {ir(k0), iz(k0), in(k0), hr(k0)}[j]
//     q=2p+1: {hz(k0), hn(k0), ir(k1), iz(k1)}[j]
//   region B (last 2048 float4 = 32 KB, stays global/L2): plane per p
//     {in(k1), hr(k1), hz(k1), hn(k1)}[j]
// gate index cc: 0=ih_r 1=ih_z 2=ih_n 3=hh_r 4=hh_z 5=hh_n
__global__ void pack_kernel(const float* __restrict__ W_ih, const float* __restrict__ W_hh,
                            float* __restrict__ Wp){
  int idx = blockIdx.x*blockDim.x + threadIdx.x; // 0..24575
  if (idx >= 96*64*4) return;
  int f = idx & 3;
  int j = (idx >> 2) & 63;
  int q = idx >> 8;          // 0..95
  int p, c;
  if (q < 64){ p = q >> 1; c = (q & 1)*4 + f; }
  else       { p = q - 64; c = 8 + f; }
  int k  = 2*p + (c >= 6 ? 1 : 0);
  int cc = c % 6;
  float val;
  if (cc < 3) val = W_ih[(cc*HID + j)*HID + k];
  else        val = W_hh[((cc-3)*HID + j)*HID + k];
  Wp[idx] = val;
}

// GCN aggregation in INPUT space, all 12 timesteps at once.
__global__ void gather_kernel(const float* __restrict__ x, const int* __restrict__ row_start,
                              const int* __restrict__ csr, const float* __restrict__ dinv,
                              float* __restrict__ rin, int N){
  int lane = threadIdx.x & 63;
  int n = blockIdx.x*4 + (threadIdx.x >> 6);
  if (n >= N) return;
  int s0 = row_start[n], s1 = row_start[n+1];
  float acc = 0.f;
  for (int e = s0; e < s1; ++e){
    int s = csr[e];
    float dv = dinv[s];
    if (lane < 24) acc += dv * x[s*24 + lane];
  }
  if (lane < 24){
    float dn = dinv[n];
    float self = x[n*24 + lane];
    rin[n*24 + lane] = dn*acc + dn*dn*self;
  }
}

// All 12 GRU steps + final FC, fused. Wave = NODES nodes; lane j = channel j.
// h stays in registers across all steps. Weights planes 0/1 in LDS, plane 2
// from L2 with manual 1-deep prefetch. Broadcasts via v_readlane (no LDS pipe).
__global__ __launch_bounds__(BLOCK, 4) void gru_all_kernel(
    const float* __restrict__ rin,
    const float* __restrict__ W_gcn, const float* __restrict__ b_gcn,
    const float* __restrict__ Wp,
    const float* __restrict__ b_ih, const float* __restrict__ b_hh,
    const float* __restrict__ W_fc, const float* __restrict__ b_fc,
    float* __restrict__ out, int N){
  __shared__ float4 wlds[4096];   // 64 KB: planes 0/1
  const float4* Wp4 = (const float4*)Wp;
  #pragma unroll
  for (int i = 0; i < 4096/BLOCK; ++i)
    wlds[i*BLOCK + threadIdx.x] = Wp4[i*BLOCK + threadIdx.x];
  __syncthreads();

  int lane = threadIdx.x & 63;
  int wid  = threadIdx.x >> 6;
  int n0 = blockIdx.x*NPB + wid*NODES;
  if (n0 >= N) return;

  float wg0 = W_gcn[lane], wg1 = W_gcn[HID+lane], bg = b_gcn[lane];
  float brz_r = b_ih[lane]       + b_hh[lane];
  float brz_z = b_ih[HID+lane]   + b_hh[HID+lane];
  float bin   = b_ih[2*HID+lane];
  float bhn   = b_hh[2*HID+lane];

  const float4* W2 = Wp4 + 4096;  // plane-2 base (global, L2-resident)

  float h[NODES];
  #pragma unroll
  for (int i = 0; i < NODES; ++i) h[i] = 0.f;

  #pragma unroll 1
  for (int t = 0; t < T_STEPS; ++t){
    float s[NODES];
    #pragma unroll
    for (int i = 0; i < NODES; ++i){
      int n = n0 + i;
      float r0 = (n < N) ? rin[n*24 + 2*t]     : 0.f;
      float r1 = (n < N) ? rin[n*24 + 2*t + 1] : 0.f;
      s[i] = fmaxf(fmaf(r0, wg0, fmaf(r1, wg1, bg)), 0.f);
    }

    float ar[NODES], az[NODES], ani[NODES], anh[NODES];
    #pragma unroll
    for (int i = 0; i < NODES; ++i){ ar[i]=0.f; az[i]=0.f; ani[i]=0.f; anh[i]=0.f; }

    float4 w2 = W2[lane];  // prefetch p=0
    #pragma unroll 1
    for (int p = 0; p < 32; ++p){
      float4 w0 = wlds[(p*2+0)*64 + lane];
      float4 w1 = wlds[(p*2+1)*64 + lane];
      float4 w2n = (p < 31) ? W2[(p+1)*64 + lane] : w2;  // prefetch next
      int k0 = 2*p, k1 = 2*p + 1;
      #pragma unroll
      for (int i = 0; i < NODES; ++i){
        float sk0 = rlane(s[i], k0);
        float hk0 = rlane(h[i], k0);
        ar[i]  = fmaf(w0.x, sk0, ar[i]);
        az[i]  = fmaf(w0.y, sk0, az[i]);
        ani[i] = fmaf(w0.z, sk0, ani[i]);
        ar[i]  = fmaf(w0.w, hk0, ar[i]);
        az[i]  = fmaf(w1.x, hk0, az[i]);
        anh[i] = fmaf(w1.y, hk0, anh[i]);
        float sk1 = rlane(s[i], k1);
        float hk1 = rlane(h[i], k1);
        ar[i]  = fmaf(w1.z, sk1, ar[i]);
        az[i]  = fmaf(w1.w, sk1, az[i]);
        ani[i] = fmaf(w2.x, sk1, ani[i]);
        ar[i]  = fmaf(w2.y, hk1, ar[i]);
        az[i]  = fmaf(w2.z, hk1, az[i]);
        anh[i] = fmaf(w2.w, hk1, anh[i]);
      }
      w2 = w2n;
    }

    #pragma unroll
    for (int i = 0; i < NODES; ++i){
      float r  = sigmoidf_(ar[i] + brz_r);
      float z  = sigmoidf_(az[i] + brz_z);
      float nn = tanhf_(ani[i] + bin + r*(anh[i] + bhn));
      h[i] = (1.0f - z)*nn + z*h[i];
    }
  }

  // fused FC
  float wfc = W_fc[lane];
  float bfc = b_fc[0];
  #pragma unroll
  for (int i = 0; i < NODES; ++i){
    float v = h[i] * wfc;
    #pragma unroll
    for (int m = 32; m >= 1; m >>= 1) v += __shfl_xor(v, m, 64);
    int n = n0 + i;
    if (lane == 0 && n < N) out[n] = v + bfc;
  }
}

extern "C" void kernel_launch(void* const* d_in, const int* in_sizes, int n_in,
                              void* d_out, int out_size, void* d_ws, size_t ws_size,
                              hipStream_t stream){
  const float* x     = (const float*)d_in[0];
  const int*   ei    = (const int*)d_in[1];
  const float* W_gcn = (const float*)d_in[2];
  const float* b_gcn = (const float*)d_in[3];
  const float* W_ih  = (const float*)d_in[4];
  const float* W_hh  = (const float*)d_in[5];
  const float* b_ih  = (const float*)d_in[6];
  const float* b_hh  = (const float*)d_in[7];
  const float* W_fc  = (const float*)d_in[8];
  const float* b_fc  = (const float*)d_in[9];
  float* out = (float*)d_out;
  const int N = in_sizes[0] / (T_STEPS*2);
  const int E = in_sizes[1] / 2;
  const int NB1024 = (N + 1023) / 1024;

  char* p = (char*)d_ws;
  auto alloc = [&](size_t bytes)->char*{
    char* r = p; p += (bytes + 255) & ~(size_t)255; return r;
  };
  int*   cnt       = (int*)  alloc((size_t)N*4);
  int*   row_start = (int*)  alloc((size_t)(N+1)*4);
  int*   cursor    = (int*)  alloc((size_t)N*4);
  int*   csr       = (int*)  alloc((size_t)E*4);
  float* dinv      = (float*)alloc((size_t)N*4);
  int*   part      = (int*)  alloc((size_t)N*4);
  int*   bsum      = (int*)  alloc((size_t)NB1024*4);
  int*   bincl     = (int*)  alloc((size_t)NB1024*4);
  float* Wp        = (float*)alloc((size_t)96*64*4*4);
  float* rin       = (float*)alloc((size_t)N*24*4);

  hipMemsetAsync(cnt, 0, (size_t)N*4, stream);
  count_kernel<<<(E+255)/256, 256, 0, stream>>>(ei, E, cnt);
  dinv_kernel<<<(N+255)/256, 256, 0, stream>>>(cnt, dinv, N);
  scan1_kernel<<<NB1024, 1024, 0, stream>>>(cnt, part, bsum, N);
  scan2_kernel<<<1, 64, 0, stream>>>(bsum, bincl, NB1024);
  scan3_kernel<<<(N+255)/256, 256, 0, stream>>>(part, bincl, cnt, row_start, cursor, N);
  fill_kernel<<<(E+255)/256, 256, 0, stream>>>(ei, E, cursor, csr);
  pack_kernel<<<(96*64*4+255)/256, 256, 0, stream>>>(W_ih, W_hh, Wp);
  gather_kernel<<<(N+3)/4, 256, 0, stream>>>(x, row_start, csr, dinv, rin, N);

  int blocks = (N + NPB - 1) / NPB;
  gru_all_kernel<<<blocks, BLOCK, 0, stream>>>(rin, W_gcn, b_gcn, Wp, b_ih, b_hh,
                                               W_fc, b_fc, out, N);
}

// Round 4
// 1093.906 us; speedup vs baseline: 1.2200x; 1.0323x over previous
//
#include <hip/hip_runtime.h>
#include <math.h>

#define T_STEPS 12
#define HID 64
#define NODES 12          // nodes per wave in gru_all
#define WPB 8             // waves per block
#define BLOCK (WPB*64)    // 512 threads
#define NPB (WPB*NODES)   // 96 nodes per block

__device__ __forceinline__ float sigmoidf_(float x){ return 1.0f/(1.0f + __expf(-x)); }
__device__ __forceinline__ float tanhf_(float x){
  float e = __expf(-2.0f * fabsf(x));
  float t = (1.0f - e) / (1.0f + e);
  return copysignf(t, x);
}
// broadcast lane l of v to all lanes via v_readlane (uniform l, no LDS pipe)
__device__ __forceinline__ float rlane(float v, int l){
  return __int_as_float(__builtin_amdgcn_readlane(__float_as_int(v), l));
}

// --- CSR build ---------------------------------------------------------
__global__ void count_kernel(const int* __restrict__ ei, int E, int* __restrict__ cnt){
  int e = blockIdx.x*blockDim.x + threadIdx.x;
  if (e < E) atomicAdd(&cnt[ei[E + e]], 1);
}

__global__ void dinv_kernel(const int* __restrict__ cnt, float* __restrict__ dinv, int N){
  int i = blockIdx.x*blockDim.x + threadIdx.x;
  if (i < N) dinv[i] = 1.0f / sqrtf((float)cnt[i] + 1.0f);
}

__global__ void scan1_kernel(const int* __restrict__ cnt, int* __restrict__ part,
                             int* __restrict__ bsum, int N){
  __shared__ int sm[1024];
  int tid = threadIdx.x;
  int g = blockIdx.x*1024 + tid;
  int v = (g < N) ? cnt[g] : 0;
  sm[tid] = v; __syncthreads();
  for (int off = 1; off < 1024; off <<= 1){
    int t = (tid >= off) ? sm[tid-off] : 0;
    __syncthreads();
    sm[tid] += t;
    __syncthreads();
  }
  if (g < N) part[g] = sm[tid];
  if (tid == 1023) bsum[blockIdx.x] = sm[1023];
}

__global__ void scan2_kernel(const int* __restrict__ bsum, int* __restrict__ bincl, int nb){
  int lane = threadIdx.x;
  int v = (lane < nb) ? bsum[lane] : 0;
  #pragma unroll
  for (int off = 1; off < 64; off <<= 1){
    int u = __shfl_up(v, off, 64);
    if (lane >= off) v += u;
  }
  if (lane < nb) bincl[lane] = v;
}

__global__ void scan3_kernel(const int* __restrict__ part, const int* __restrict__ bincl,
                             const int* __restrict__ cnt, int* __restrict__ row_start,
                             int* __restrict__ cursor, int N){
  int g = blockIdx.x*blockDim.x + threadIdx.x;
  if (g < N){
    int b = g >> 10;
    int incl = part[g] + (b ? bincl[b-1] : 0);
    int excl = incl - cnt[g];
    row_start[g] = excl;
    cursor[g]    = excl;
    if (g == N-1) row_start[N] = incl;
  }
}

__global__ void fill_kernel(const int* __restrict__ ei, int E,
                            int* __restrict__ cursor, int* __restrict__ csr){
  int e = blockIdx.x*blockDim.x + threadIdx.x;
  if (e < E){
    int dst = ei[E + e];
    int pos = atomicAdd(&cursor[dst], 1);
    csr[pos] = ei[e];  // src
  }
}

// Pack W_ih/W_hh (each 192x64 row-major) into:
//   region A (first 4096 float4 = 64 KB, goes to LDS): for each pair p, two planes
//     q=2p:   {ir(k0), iz(k0), in(k0), hr(k0)}[j]
//     q=2p+1: {hz(k0), hn(k0), ir(k1), iz(k1)}[j]
//   region B (last 2048 float4 = 32 KB, stays global/L2): plane per p
//     {in(k1), hr(k1), hz(k1), hn(k1)}[j]
__global__ void pack_kernel(const float* __restrict__ W_ih, const float* __restrict__ W_hh,
                            float* __restrict__ Wp){
  int idx = blockIdx.x*blockDim.x + threadIdx.x; // 0..24575
  if (idx >= 96*64*4) return;
  int f = idx & 3;
  int j = (idx >> 2) & 63;
  int q = idx >> 8;          // 0..95
  int p, c;
  if (q < 64){ p = q >> 1; c = (q & 1)*4 + f; }
  else       { p = q - 64; c = 8 + f; }
  int k  = 2*p + (c >= 6 ? 1 : 0);
  int cc = c % 6;
  float val;
  if (cc < 3) val = W_ih[(cc*HID + j)*HID + k];
  else        val = W_hh[((cc-3)*HID + j)*HID + k];
  Wp[idx] = val;
}

// GCN aggregation in INPUT space, all 12 timesteps at once.
__global__ void gather_kernel(const float* __restrict__ x, const int* __restrict__ row_start,
                              const int* __restrict__ csr, const float* __restrict__ dinv,
                              float* __restrict__ rin, int N){
  int lane = threadIdx.x & 63;
  int n = blockIdx.x*4 + (threadIdx.x >> 6);
  if (n >= N) return;
  int s0 = row_start[n], s1 = row_start[n+1];
  float acc = 0.f;
  for (int e = s0; e < s1; ++e){
    int s = csr[e];
    float dv = dinv[s];
    if (lane < 24) acc += dv * x[s*24 + lane];
  }
  if (lane < 24){
    float dn = dinv[n];
    float self = x[n*24 + lane];
    rin[n*24 + lane] = dn*acc + dn*dn*self;
  }
}

// All 12 GRU steps + final FC, fused. Wave = NODES nodes; lane j = channel j.
// h stays in registers across all steps. Weights planes 0/1 in LDS, plane 2
// from L2 with manual 1-deep prefetch. Broadcasts via v_readlane.
// __launch_bounds__(512, 2): 2 blocks/CU * 8 waves = 4 waves/EU -> 128 VGPR cap.
// (512,4) capped VGPRs at 64 and spilled ~7 GB/launch to scratch (round 3).
__global__ __launch_bounds__(BLOCK, 2) void gru_all_kernel(
    const float* __restrict__ rin,
    const float* __restrict__ W_gcn, const float* __restrict__ b_gcn,
    const float* __restrict__ Wp,
    const float* __restrict__ b_ih, const float* __restrict__ b_hh,
    const float* __restrict__ W_fc, const float* __restrict__ b_fc,
    float* __restrict__ out, int N){
  __shared__ float4 wlds[4096];   // 64 KB: planes 0/1
  const float4* Wp4 = (const float4*)Wp;
  #pragma unroll
  for (int i = 0; i < 4096/BLOCK; ++i)
    wlds[i*BLOCK + threadIdx.x] = Wp4[i*BLOCK + threadIdx.x];
  __syncthreads();

  int lane = threadIdx.x & 63;
  int wid  = threadIdx.x >> 6;
  int n0 = blockIdx.x*NPB + wid*NODES;
  if (n0 >= N) return;

  float wg0 = W_gcn[lane], wg1 = W_gcn[HID+lane], bg = b_gcn[lane];
  float brz_r = b_ih[lane]       + b_hh[lane];
  float brz_z = b_ih[HID+lane]   + b_hh[HID+lane];
  float bin   = b_ih[2*HID+lane];
  float bhn   = b_hh[2*HID+lane];

  const float4* W2 = Wp4 + 4096;  // plane-2 base (global, L2-resident)

  float h[NODES];
  #pragma unroll
  for (int i = 0; i < NODES; ++i) h[i] = 0.f;

  #pragma unroll 1
  for (int t = 0; t < T_STEPS; ++t){
    float s[NODES];
    #pragma unroll
    for (int i = 0; i < NODES; ++i){
      int n = n0 + i;
      float r0 = (n < N) ? rin[n*24 + 2*t]     : 0.f;
      float r1 = (n < N) ? rin[n*24 + 2*t + 1] : 0.f;
      s[i] = fmaxf(fmaf(r0, wg0, fmaf(r1, wg1, bg)), 0.f);
    }

    float ar[NODES], az[NODES], ani[NODES], anh[NODES];
    #pragma unroll
    for (int i = 0; i < NODES; ++i){ ar[i]=0.f; az[i]=0.f; ani[i]=0.f; anh[i]=0.f; }

    float4 w2 = W2[lane];  // prefetch p=0
    #pragma unroll 1
    for (int p = 0; p < 32; ++p){
      float4 w0 = wlds[(p*2+0)*64 + lane];
      float4 w1 = wlds[(p*2+1)*64 + lane];
      float4 w2n = (p < 31) ? W2[(p+1)*64 + lane] : w2;  // prefetch next
      int k0 = 2*p, k1 = 2*p + 1;
      #pragma unroll
      for (int i = 0; i < NODES; ++i){
        float sk0 = rlane(s[i], k0);
        float hk0 = rlane(h[i], k0);
        ar[i]  = fmaf(w0.x, sk0, ar[i]);
        az[i]  = fmaf(w0.y, sk0, az[i]);
        ani[i] = fmaf(w0.z, sk0, ani[i]);
        ar[i]  = fmaf(w0.w, hk0, ar[i]);
        az[i]  = fmaf(w1.x, hk0, az[i]);
        anh[i] = fmaf(w1.y, hk0, anh[i]);
        float sk1 = rlane(s[i], k1);
        float hk1 = rlane(h[i], k1);
        ar[i]  = fmaf(w1.z, sk1, ar[i]);
        az[i]  = fmaf(w1.w, sk1, az[i]);
        ani[i] = fmaf(w2.x, sk1, ani[i]);
        ar[i]  = fmaf(w2.y, hk1, ar[i]);
        az[i]  = fmaf(w2.z, hk1, az[i]);
        anh[i] = fmaf(w2.w, hk1, anh[i]);
      }
      w2 = w2n;
    }

    #pragma unroll
    for (int i = 0; i < NODES; ++i){
      float r  = sigmoidf_(ar[i] + brz_r);
      float z  = sigmoidf_(az[i] + brz_z);
      float nn = tanhf_(ani[i] + bin + r*(anh[i] + bhn));
      h[i] = (1.0f - z)*nn + z*h[i];
    }
  }

  // fused FC
  float wfc = W_fc[lane];
  float bfc = b_fc[0];
  #pragma unroll
  for (int i = 0; i < NODES; ++i){
    float v = h[i] * wfc;
    #pragma unroll
    for (int m = 32; m >= 1; m >>= 1) v += __shfl_xor(v, m, 64);
    int n = n0 + i;
    if (lane == 0 && n < N) out[n] = v + bfc;
  }
}

extern "C" void kernel_launch(void* const* d_in, const int* in_sizes, int n_in,
                              void* d_out, int out_size, void* d_ws, size_t ws_size,
                              hipStream_t stream){
  const float* x     = (const float*)d_in[0];
  const int*   ei    = (const int*)d_in[1];
  const float* W_gcn = (const float*)d_in[2];
  const float* b_gcn = (const float*)d_in[3];
  const float* W_ih  = (const float*)d_in[4];
  const float* W_hh  = (const float*)d_in[5];
  const float* b_ih  = (const float*)d_in[6];
  const float* b_hh  = (const float*)d_in[7];
  const float* W_fc  = (const float*)d_in[8];
  const float* b_fc  = (const float*)d_in[9];
  float* out = (float*)d_out;
  const int N = in_sizes[0] / (T_STEPS*2);
  const int E = in_sizes[1] / 2;
  const int NB1024 = (N + 1023) / 1024;

  char* p = (char*)d_ws;
  auto alloc = [&](size_t bytes)->char*{
    char* r = p; p += (bytes + 255) & ~(size_t)255; return r;
  };
  int*   cnt       = (int*)  alloc((size_t)N*4);
  int*   row_start = (int*)  alloc((size_t)(N+1)*4);
  int*   cursor    = (int*)  alloc((size_t)N*4);
  int*   csr       = (int*)  alloc((size_t)E*4);
  float* dinv      = (float*)alloc((size_t)N*4);
  int*   part      = (int*)  alloc((size_t)N*4);
  int*   bsum      = (int*)  alloc((size_t)NB1024*4);
  int*   bincl     = (int*)  alloc((size_t)NB1024*4);
  float* Wp        = (float*)alloc((size_t)96*64*4*4);
  float* rin       = (float*)alloc((size_t)N*24*4);

  hipMemsetAsync(cnt, 0, (size_t)N*4, stream);
  count_kernel<<<(E+255)/256, 256, 0, stream>>>(ei, E, cnt);
  dinv_kernel<<<(N+255)/256, 256, 0, stream>>>(cnt, dinv, N);
  scan1_kernel<<<NB1024, 1024, 0, stream>>>(cnt, part, bsum, N);
  scan2_kernel<<<1, 64, 0, stream>>>(bsum, bincl, NB1024);
  scan3_kernel<<<(N+255)/256, 256, 0, stream>>>(part, bincl, cnt, row_start, cursor, N);
  fill_kernel<<<(E+255)/256, 256, 0, stream>>>(ei, E, cursor, csr);
  pack_kernel<<<(96*64*4+255)/256, 256, 0, stream>>>(W_ih, W_hh, Wp);
  gather_kernel<<<(N+3)/4, 256, 0, stream>>>(x, row_start, csr, dinv, rin, N);

  int blocks = (N + NPB - 1) / NPB;
  gru_all_kernel<<<blocks, BLOCK, 0, stream>>>(rin, W_gcn, b_gcn, Wp, b_ih, b_hh,
                                               W_fc, b_fc, out, N);
}